// Round 7
// baseline (564.343 us; speedup 1.0000x reference)
//
#include <hip/hip_runtime.h>
#include <hip/hip_bf16.h>
#include <stdint.h>

#define H2    512
#define BATCH 32
#define SEQ   4096
#define BM    64

typedef __attribute__((ext_vector_type(4))) float f32x4;
typedef __attribute__((ext_vector_type(8))) short bf16x8;

__device__ __forceinline__ unsigned short f2bf(float f) {
    union { float f; unsigned u; } v; v.f = f;
    unsigned r = v.u + 0x7FFF + ((v.u >> 16) & 1);
    return (unsigned short)(r >> 16);
}

__device__ __forceinline__ uint2 cvt4_bf16(f32x4 a) {
    uint2 r;
    asm("v_cvt_pk_bf16_f32 %0, %1, %2" : "=v"(r.x) : "v"(a[0]), "v"(a[1]));
    asm("v_cvt_pk_bf16_f32 %0, %1, %2" : "=v"(r.y) : "v"(a[2]), "v"(a[3]));
    return r;
}

__device__ __forceinline__ float fast_tanh(float x) {
    float e = __builtin_amdgcn_exp2f(x * 2.88539008177793f);
    return 1.0f - 2.0f * __builtin_amdgcn_rcpf(e + 1.0f);
}

// ---------------------------------------------------------------------------
// Prep 1: W = [W_h; W_c] -> bf16 FRAGMENT-MAJOR (layout unchanged from R5):
// chunk c = (kt32*32 + cb)*64 + lane holds 16B:
//   B[col = cb*16 + (lane&15)][k = kt32*32 + (lane>>4)*8 + j], j=0..7
// ---------------------------------------------------------------------------
__global__ void kprep_w(const float* __restrict__ Wh, const float* __restrict__ Wc,
                        unsigned short* __restrict__ wt) {
    int c    = blockIdx.x * blockDim.x + threadIdx.x;   // 65536 chunks
    int lane = c & 63;
    int cb   = (c >> 6) & 31;
    int kt   = c >> 11;                                  // 0..31
    int col  = cb * 16 + (lane & 15);
    int k0   = kt * 32 + (lane >> 4) * 8;
    unsigned short tmp[8];
#pragma unroll
    for (int j = 0; j < 8; ++j) {
        int kg = k0 + j;
        float w = (kg < 512) ? Wh[kg * 512 + col] : Wc[(kg - 512) * 512 + col];
        tmp[j] = f2bf(w);
    }
    *reinterpret_cast<uint4*>(wt + (size_t)c * 8) = *reinterpret_cast<const uint4*>(tmp);
}

// ---------------------------------------------------------------------------
// Prep 2: q[b][h] = dec[b]@W_s + b_h + b_s + b_c
// ---------------------------------------------------------------------------
__global__ void kprep_q(const float* __restrict__ dec, const float* __restrict__ Ws,
                        const float* __restrict__ bh, const float* __restrict__ bs,
                        const float* __restrict__ bc, float* __restrict__ q) {
    __shared__ float dsh[512];
    int b = blockIdx.x, t = threadIdx.x;               // 256 threads
    dsh[t]       = dec[b * 512 + t];
    dsh[t + 256] = dec[b * 512 + 256 + t];
    __syncthreads();
    float a0 = 0.f, a1 = 0.f;
#pragma unroll 4
    for (int k = 0; k < 512; ++k) {
        float d = dsh[k];
        a0 = fmaf(d, Ws[k * 512 + t], a0);
        a1 = fmaf(d, Ws[k * 512 + 256 + t], a1);
    }
    q[b * 512 + t]       = a0 + bh[t] + bs[t] + bc[t];
    q[b * 512 + 256 + t] = a1 + bh[256 + t] + bs[256 + t] + bc[256 + t];
}

// ---------------------------------------------------------------------------
// Main fused GEMM v6: K=128 super-tiles, ONE barrier per super-tile (8 total,
// was 32). Inside: 4 barrier-free sub-tiles {ds_read af | LOAD_B(next) |
// 16 MFMA}. A(st+1) staged in two 32B halves (pa = 8 VGPR), issue/write
// placed so HBM loads rarely poison the counted B vmcnt waits.
// Budget: arch VGPR <= 64 (+64 acc) -> 2 blocks/CU preserved.
// ---------------------------------------------------------------------------
__launch_bounds__(512, 4)
__global__ void kgemm(const float* __restrict__ enc, const float* __restrict__ cov,
                      const unsigned short* __restrict__ wt,
                      const float* __restrict__ q, const float* __restrict__ vvec,
                      float* __restrict__ scores) {
    __shared__ unsigned short Asm[2][8192];   // 2 x 16KB: 4 subs x 4KB frag-major
    __shared__ float qv[H2];
    __shared__ float vv[H2];
    __shared__ float sred[BM][8];

    int tid  = threadIdx.x;
    int lane = tid & 63, wn = tid >> 6;

    int cpx  = gridDim.x >> 3;
    int swz  = (blockIdx.x & 7) * cpx + (blockIdx.x >> 3);
    int row0 = swz * BM;

    // A staging: thread t -> row r = t>>3, k-octet k8 = t&7 (8 floats = 32B)
    int r = tid >> 3, k8 = tid & 7;
    const float* aeb = enc + (size_t)(row0 + r) * H2;
    const float* acb = cov + (size_t)(row0 + r) * H2;
    unsigned awq = (unsigned)((r >> 4) * 1024 + (k8 & 3) * 256 +
                              (((r & 15) * 16) ^ ((k8 & 3) << 4)));
    unsigned aw0 = ((k8 >> 2) + 0) * 4096 + awq;   // half 0 -> subs {0,1}
    unsigned aw1 = ((k8 >> 2) + 2) * 4096 + awq;   // half 1 -> subs {2,3}
    unsigned arb = (unsigned)((lane >> 4) * 256 +
                              (((lane & 15) * 16) ^ ((lane >> 4) << 4)));
    const bf16x8* bb = reinterpret_cast<const bf16x8*>(wt) +
                       (size_t)(wn * 4) * 64 + lane;

    f32x4  acc[4][4] = {};
    bf16x8 bfr[4];
    bf16x8 af[4];
    f32x4  pa0, pa1;

#define DS_AF(CUR, S)                                                          \
    _Pragma("unroll")                                                          \
    for (int mi = 0; mi < 4; ++mi)                                             \
        af[mi] = *reinterpret_cast<const bf16x8*>(                             \
            (char*)Asm + (CUR) * 16384 + (S) * 4096 + mi * 1024 + arb);
#define LOAD_B(KT)                                                             \
    { const int _kt = (KT);                                                    \
      _Pragma("unroll")                                                        \
      for (int ni = 0; ni < 4; ++ni)                                           \
          bfr[ni] = bb[(size_t)_kt * 2048 + ni * 64]; }
#define MFMA16                                                                 \
    __builtin_amdgcn_s_setprio(1);                                             \
    _Pragma("unroll")                                                          \
    for (int mi = 0; mi < 4; ++mi)                                             \
        _Pragma("unroll")                                                      \
        for (int ni = 0; ni < 4; ++ni)                                         \
            acc[mi][ni] = __builtin_amdgcn_mfma_f32_16x16x32_bf16(             \
                af[mi], bfr[ni], acc[mi][ni], 0, 0, 0);                        \
    __builtin_amdgcn_s_setprio(0);
#define ISSUE_A(ST1, H)                                                        \
    { int _c = (ST1) * 128 + (H) * 64 + k8 * 8;                                \
      const float* _p = (_c < 512) ? (aeb + _c) : (acb + (_c - 512));          \
      pa0 = *reinterpret_cast<const f32x4*>(_p);                               \
      pa1 = *reinterpret_cast<const f32x4*>(_p + 4); }
#define WRITE_A(BUF, AW)                                                       \
    { uint2 _u0 = cvt4_bf16(pa0); uint2 _u1 = cvt4_bf16(pa1);                  \
      uint4 _u; _u.x = _u0.x; _u.y = _u0.y; _u.z = _u1.x; _u.w = _u1.y;        \
      *reinterpret_cast<uint4*>((char*)Asm + (BUF) * 16384 + (AW)) = _u; }
#define SB0 __builtin_amdgcn_sched_barrier(0);
#define FENCE_BAR                                                              \
    asm volatile("s_waitcnt lgkmcnt(0)" ::: "memory");                         \
    SB0 __builtin_amdgcn_s_barrier(); SB0

#define BODY(ST, CUR, MORE)                                                    \
  {                                                                            \
    const int kt0 = (ST) * 4;                                                  \
    DS_AF(CUR, 0)                                                              \
    MFMA16                                                                     \
    SB0                                                                        \
    DS_AF(CUR, 1)                                                              \
    LOAD_B(kt0 + 1)                                                            \
    if (MORE) { ISSUE_A((ST) + 1, 0) }                                         \
    SB0                                                                        \
    MFMA16                                                                     \
    SB0                                                                        \
    DS_AF(CUR, 2)                                                              \
    LOAD_B(kt0 + 2)                                                            \
    SB0                                                                        \
    MFMA16                                                                     \
    SB0                                                                        \
    DS_AF(CUR, 3)                                                              \
    LOAD_B(kt0 + 3)                                                            \
    if (MORE) { WRITE_A((CUR) ^ 1, aw0) ISSUE_A((ST) + 1, 1) }                 \
    SB0                                                                        \
    MFMA16                                                                     \
    SB0                                                                        \
    LOAD_B((kt0 + 4 < 32) ? kt0 + 4 : 31)                                      \
    if (MORE) { WRITE_A((CUR) ^ 1, aw1) }                                      \
    FENCE_BAR                                                                  \
  }

    // ---- prologue: B(0) -> regs; stage A(0) (both halves, sequential) ----
    LOAD_B(0)
    ISSUE_A(0, 0)
    WRITE_A(0, aw0)
    ISSUE_A(0, 1)
    WRITE_A(0, aw1)
    FENCE_BAR

    // ---- 8 super-tiles, pair-unrolled for compile-time buffer parity ----
#pragma unroll 1
    for (int stp = 0; stp < 4; ++stp) {
        const int st0 = stp * 2;
        BODY(st0, 0, true)
        BODY(st0 + 1, 1, (stp < 3))
    }

#undef DS_AF
#undef LOAD_B
#undef MFMA16
#undef ISSUE_A
#undef WRITE_A
#undef SB0
#undef FENCE_BAR
#undef BODY

    // ---- epilogue: tanh(x + q) * v, reduce over 512 cols -> scores ----
    qv[tid] = q[(row0 >> 12) * H2 + tid];
    vv[tid] = vvec[tid];
    __syncthreads();

    float ps[4][4] = {};
#pragma unroll
    for (int mi = 0; mi < 4; ++mi)
#pragma unroll
        for (int ni = 0; ni < 4; ++ni) {
            int colg = wn * 64 + ni * 16 + (lane & 15);
            float qq = qv[colg], vl = vv[colg];
#pragma unroll
            for (int j = 0; j < 4; ++j) {
                float e = fast_tanh(acc[mi][ni][j] + qq);
                ps[mi][j] = fmaf(e, vl, ps[mi][j]);
            }
        }
#pragma unroll
    for (int mi = 0; mi < 4; ++mi)
#pragma unroll
        for (int j = 0; j < 4; ++j) {
            float s = ps[mi][j];
            s += __shfl_xor(s, 1);
            s += __shfl_xor(s, 2);
            s += __shfl_xor(s, 4);
            s += __shfl_xor(s, 8);
            if ((lane & 15) == 0)
                sred[mi * 16 + (lane >> 4) * 4 + j][wn] = s;
        }
    __syncthreads();
    if (tid < BM) {
        float s = 0.f;
#pragma unroll
        for (int w = 0; w < 8; ++w) s += sred[tid][w];
        scores[row0 + tid] = s;
    }
}

// ---------------------------------------------------------------------------
// Softmax over S per batch; also zeroes h_star (atomic target for kcov).
// ---------------------------------------------------------------------------
__global__ void ksoftmax(const float* __restrict__ scores, float* __restrict__ out) {
    __shared__ float redm[16];
    __shared__ float reds[16];
    int b = blockIdx.x, t = threadIdx.x, lane = t & 63, w = t >> 6;  // 1024 thr
    if (t < 512) out[b * 512 + t] = 0.0f;                            // zero h_star
    f32x4 sv = *reinterpret_cast<const f32x4*>(scores + b * 4096 + t * 4);
    float m = fmaxf(fmaxf(sv[0], sv[1]), fmaxf(sv[2], sv[3]));
#pragma unroll
    for (int o = 1; o < 64; o <<= 1) m = fmaxf(m, __shfl_xor(m, o));
    if (lane == 0) redm[w] = m;
    __syncthreads();
    float mm = redm[0];
#pragma unroll
    for (int i = 1; i < 16; ++i) mm = fmaxf(mm, redm[i]);

    f32x4 p;
#pragma unroll
    for (int j = 0; j < 4; ++j)
        p[j] = __builtin_amdgcn_exp2f((sv[j] - mm) * 1.4426950408889634f);
    float s = p[0] + p[1] + p[2] + p[3];
#pragma unroll
    for (int o = 1; o < 64; o <<= 1) s += __shfl_xor(s, o);
    if (lane == 0) reds[w] = s;
    __syncthreads();
    float tot = 0.f;
#pragma unroll
    for (int i = 0; i < 16; ++i) tot += reds[i];
    float rinv = __builtin_amdgcn_rcpf(tot);
    p *= rinv;
    *reinterpret_cast<f32x4*>(out + 16384 + b * 4096 + t * 4) = p;
}

// ---------------------------------------------------------------------------
// coverage_new = cov + attn (broadcast) ; h_star = sum_s attn * enc (atomic)
// ---------------------------------------------------------------------------
__global__ void kcov(const float* __restrict__ enc, const float* __restrict__ cov,
                     float* __restrict__ out) {
    const float* attn = out + 16384;
    float* covn  = out + 16384 + 131072;
    float* hstar = out;
    int blk = blockIdx.x;                    // 2048 = 32 b * 64 chunks
    int b = blk >> 6, ck = blk & 63;
    int s0 = ck * 64;
    int t  = threadIdx.x;                    // 256
    int f4 = (t & 127) * 4;
    int rp = t >> 7;
    size_t base = (size_t)b * SEQ * H2;
    f32x4 h = {0.f, 0.f, 0.f, 0.f};
#pragma unroll 2
    for (int i = 0; i < 32; ++i) {
        int s = s0 + i * 2 + rp;
        float a = attn[b * 4096 + s];
        size_t idx = base + (size_t)s * H2 + f4;
        f32x4 e4 = *reinterpret_cast<const f32x4*>(enc + idx);
        f32x4 c4 = *reinterpret_cast<const f32x4*>(cov + idx);
        c4 += a;
        __builtin_nontemporal_store(c4, reinterpret_cast<f32x4*>(covn + idx));
        h += a * e4;
    }
    int off = b * 512 + f4;
    atomicAdd(&hstar[off + 0], h[0]);
    atomicAdd(&hstar[off + 1], h[1]);
    atomicAdd(&hstar[off + 2], h[2]);
    atomicAdd(&hstar[off + 3], h[3]);
}

extern "C" void kernel_launch(void* const* d_in, const int* in_sizes, int n_in,
                              void* d_out, int out_size, void* d_ws, size_t ws_size,
                              hipStream_t stream) {
    const float* dec = (const float*)d_in[0];
    const float* enc = (const float*)d_in[1];
    const float* cov = (const float*)d_in[2];
    const float* Wh  = (const float*)d_in[3];
    const float* bh  = (const float*)d_in[4];
    const float* Ws  = (const float*)d_in[5];
    const float* bs  = (const float*)d_in[6];
    const float* Wc  = (const float*)d_in[7];
    const float* bc  = (const float*)d_in[8];
    const float* v   = (const float*)d_in[9];
    float* out = (float*)d_out;

    char* ws = (char*)d_ws;
    unsigned short* wt = (unsigned short*)ws;                 // 1 MB bf16 weights
    float* q      = (float*)(ws + (1 << 20));                 // 64 KB
    float* scores = (float*)(ws + (1 << 20) + 65536);         // 512 KB

    kprep_w <<<dim3(256),  dim3(256),  0, stream>>>(Wh, Wc, wt);
    kprep_q <<<dim3(32),   dim3(256),  0, stream>>>(dec, Ws, bh, bs, bc, q);
    kgemm   <<<dim3(2048), dim3(512),  0, stream>>>(enc, cov, wt, q, v, scores);
    ksoftmax<<<dim3(32),   dim3(1024), 0, stream>>>(scores, out);
    kcov    <<<dim3(2048), dim3(256),  0, stream>>>(enc, cov, out);
}